// Round 1
// baseline (1775.609 us; speedup 1.0000x reference)
//
#include <hip/hip_runtime.h>
#include <hip/hip_bf16.h>

// Fused attention: B=2,H=16,S=2048,D=64; outputs (out[B,H,S,D], p_attn[B,H,S,S]) fp32.
// Single kernel, grid (bh=32, qtile=32), 256 threads (4 waves), wave owns 16 q-rows.
// Pass 1: swapped QK^T (mfma(K,Q)) -> e, row-sums in registers (NO global writes).
// Pass 2: recompute e (bitwise identical), normalize, write p once (float4),
//         LDS-bounce to PV A-frag layout, PV MFMA, write out.
#define BH_N   32
#define S_LEN  2048
#define D_DIM  64
#define SCALE_F 0.125f
#define LDSS   68   // 64 + 4 pad: uniform bank spread for b128 ops

typedef short bf16x8 __attribute__((ext_vector_type(8)));
typedef float f32x4  __attribute__((ext_vector_type(4)));

__device__ __forceinline__ short f2bf(float x) {
    union { __hip_bfloat16 h; short s; } u;
    u.h = __float2bfloat16(x);   // RNE
    return u.s;
}

__device__ __forceinline__ bf16x8 pack8(const float4 v0, const float4 v1) {
    bf16x8 r;
    r[0] = f2bf(v0.x); r[1] = f2bf(v0.y); r[2] = f2bf(v0.z); r[3] = f2bf(v0.w);
    r[4] = f2bf(v1.x); r[5] = f2bf(v1.y); r[6] = f2bf(v1.z); r[7] = f2bf(v1.w);
    return r;
}

__global__ __launch_bounds__(256) void attn_fused(
    const float* __restrict__ Q, const float* __restrict__ Km,
    const float* __restrict__ V, const int* __restrict__ mask,
    const float* __restrict__ adj, float* __restrict__ out,
    float* __restrict__ p)
{
    const int bh    = blockIdx.x;       // bh fastest: same-b blocks share mask stripe in L2/L3
    const int qtile = blockIdx.y;
    const int b     = bh >> 4;          // H = 16
    const int wave  = threadIdx.x >> 6;
    const int lane  = threadIdx.x & 63;
    const int l16   = lane & 15;
    const int quad  = lane >> 4;
    const int qw    = qtile * 64 + wave * 16;   // wave's first q row

    __shared__ __align__(16) float lds_p[4][16][LDSS];

    // Q fragment = B-operand of swapped QK^T: B[n=q_local=l16][k=quad*8+j], two D-halves
    const float* qrow = Q + ((size_t)bh * S_LEN + qw + l16) * D_DIM + quad * 8;
    bf16x8 qf[2];
    #pragma unroll
    for (int kh = 0; kh < 2; ++kh)
        qf[kh] = pack8(*(const float4*)(qrow + kh * 32),
                       *(const float4*)(qrow + kh * 32 + 4));

    const float* kbase   = Km  + (size_t)bh * S_LEN * D_DIM;
    const float* adj_row = adj + ((size_t)bh * S_LEN + qw + l16) * S_LEN;
    const int*   msk_row = mask + ((size_t)b  * S_LEN + qw + l16) * S_LEN;

    // Swapped tile: D[m=k_local][n=q_local] = sum_d K[k][d] Q[q][d].
    // Lane (quad,l16) holds q = qw+l16 (fixed!), k = kb + nt*16 + quad*4 + r.
    // => adj/mask reads and e values are 4-consecutive-k per lane: float4/int4.
    auto tile_e = [&](int kb, float (&e)[4][4]) {
        #pragma unroll
        for (int nt = 0; nt < 4; ++nt) {
            const float* krow = kbase + (size_t)(kb + nt * 16 + l16) * D_DIM + quad * 8;
            f32x4 acc = {0.f, 0.f, 0.f, 0.f};
            #pragma unroll
            for (int kh = 0; kh < 2; ++kh) {
                const bf16x8 kf = pack8(*(const float4*)(krow + kh * 32),
                                        *(const float4*)(krow + kh * 32 + 4));
                acc = __builtin_amdgcn_mfma_f32_16x16x32_bf16(kf, qf[kh], acc, 0, 0, 0);
            }
            const int kc = kb + nt * 16 + quad * 4;
            const float4 a4 = *(const float4*)(adj_row + kc);
            const int4   m4 = *(const int4*)(msk_row + kc);
            e[nt][0] = m4.x ? 0.f : __expf((acc[0] + a4.x) * SCALE_F);
            e[nt][1] = m4.y ? 0.f : __expf((acc[1] + a4.y) * SCALE_F);
            e[nt][2] = m4.z ? 0.f : __expf((acc[2] + a4.z) * SCALE_F);
            e[nt][3] = m4.w ? 0.f : __expf((acc[3] + a4.w) * SCALE_F);
        }
    };

    // ---- pass 1: row sums only (no global writes)
    float rs = 0.f;
    for (int kb = 0; kb < S_LEN; kb += 64) {
        float e[4][4];
        tile_e(kb, e);
        #pragma unroll
        for (int nt = 0; nt < 4; ++nt)
            rs += (e[nt][0] + e[nt][1]) + (e[nt][2] + e[nt][3]);
    }
    // reduce over quads (lanes with same l16 hold same q): xor 16, 32
    rs += __shfl_xor(rs, 16);
    rs += __shfl_xor(rs, 32);
    const float inv_l = 1.0f / rs;

    // ---- pass 2: recompute e (bitwise identical), normalize, write p, PV
    f32x4 oacc[4];
    #pragma unroll
    for (int nd = 0; nd < 4; ++nd) oacc[nd] = (f32x4){0.f, 0.f, 0.f, 0.f};

    float*       prow = p + ((size_t)bh * S_LEN + qw + l16) * S_LEN;
    const float* vb   = V + (size_t)bh * S_LEN * D_DIM;

    for (int kb = 0; kb < S_LEN; kb += 64) {
        float e[4][4];
        tile_e(kb, e);

        // swapped layout -> LDS (normalized): lds[q_local=l16][k_local]
        #pragma unroll
        for (int nt = 0; nt < 4; ++nt) {
            f32x4 pn = { e[nt][0] * inv_l, e[nt][1] * inv_l,
                         e[nt][2] * inv_l, e[nt][3] * inv_l };
            *(f32x4*)&lds_p[wave][l16][nt * 16 + quad * 4] = pn;
        }
        // same-wave LDS bounce; compiler inserts lgkmcnt waits, no barrier needed
        #pragma unroll
        for (int c = 0; c < 2; ++c) {
            const float* lsrc = &lds_p[wave][l16][c * 32 + quad * 8];
            const float4 p0 = *(const float4*)lsrc;
            const float4 p1 = *(const float4*)(lsrc + 4);
            // final p_attn write (only write of p; 128B/row per chunk across quads)
            *(float4*)(prow + kb + c * 32 + quad * 8)     = p0;
            *(float4*)(prow + kb + c * 32 + quad * 8 + 4) = p1;
            // PV: A[m=q_local=l16][k=quad*8+j]
            const bf16x8 a = pack8(p0, p1);
            const float* vrow = vb + (size_t)(kb + c * 32 + quad * 8) * D_DIM + l16;
            #pragma unroll
            for (int nd = 0; nd < 4; ++nd) {
                bf16x8 bv;
                #pragma unroll
                for (int j = 0; j < 8; ++j)
                    bv[j] = f2bf(vrow[(size_t)j * D_DIM + nd * 16]);
                oacc[nd] = __builtin_amdgcn_mfma_f32_16x16x32_bf16(a, bv, oacc[nd], 0, 0, 0);
            }
        }
    }

    #pragma unroll
    for (int nd = 0; nd < 4; ++nd) {
        #pragma unroll
        for (int r = 0; r < 4; ++r) {
            out[((size_t)bh * S_LEN + qw + quad * 4 + r) * D_DIM + nd * 16 + l16] =
                oacc[nd][r];
        }
    }
}

extern "C" void kernel_launch(void* const* d_in, const int* in_sizes, int n_in,
                              void* d_out, int out_size, void* d_ws, size_t ws_size,
                              hipStream_t stream) {
    const float* Q    = (const float*)d_in[0];
    const float* Km   = (const float*)d_in[1];
    const float* V    = (const float*)d_in[2];
    const int*   mask = (const int*)d_in[3];
    const float* adj  = (const float*)d_in[4];

    float* out = (float*)d_out;                       // [B,H,S,D]
    float* p   = out + (size_t)BH_N * S_LEN * D_DIM;  // [B,H,S,S]

    attn_fused<<<dim3(BH_N, S_LEN / 64), 256, 0, stream>>>(
        Q, Km, V, mask, adj, out, p);
}